// Round 22
// baseline (14.791 us; speedup 1.0000x reference)
//
#include <hip/hip_runtime.h>

#define CIN 64
#define COUT 96
#define HW_  1024
#define NTHR 512
#define NITER 5
#define NMF_EPS 1e-20f

// Round-22: 2 blocks/CU (grid 512, 8 real px/block). Fragment N=16 kept full
// by duplicating the 8 pixels into cols 8-15 (x clamped px&7 -> cols 8-15 are
// clean duplicates; out-store guarded px<8). Two barrier domains per CU
// overlap S1/S2 drains. Per-block one-time cost is only ~10 L2-hot global
// loads/thread (no LDS W staging - R15's regression trap avoided).
typedef short bf16x8 __attribute__((ext_vector_type(8)));
typedef float f32x4  __attribute__((ext_vector_type(4)));

__device__ __forceinline__ unsigned short bf_hi(float x) {
    return (unsigned short)(__float_as_uint(x) >> 16);
}
__device__ __forceinline__ float bf_f(unsigned short u) {
    return __uint_as_float(((unsigned int)u) << 16);
}
__device__ __forceinline__ unsigned short bf_rn(float x) {
    unsigned int b = __float_as_uint(x);
    b += 0x7FFF + ((b >> 16) & 1);
    return (unsigned short)(b >> 16);
}
__device__ __forceinline__ void split8(const float* v, bf16x8& hi, bf16x8& lo) {
    #pragma unroll
    for (int e = 0; e < 8; ++e) {
        const unsigned short h = bf_hi(v[e]);
        hi[e] = (short)h;
        lo[e] = (short)bf_rn(v[e] - bf_f(h));
    }
}

__global__ __launch_bounds__(NTHR) void nmf_kernel(
    const float* __restrict__ x,
    const float* __restrict__ w,
    const float* __restrict__ h0,
    float* __restrict__ out)
{
    __shared__ unsigned short Hb_hi[16][104], Hb_lo[16][104];  // H as [pxcol][j]
    __shared__ unsigned short Tb_hi[16][72],  Tb_lo[16][72];   // T as [pxcol][i]
    __shared__ float Par[6][16];

    const int t    = threadIdx.x;
    const int wid  = t >> 6;
    const int l    = t & 63;
    const int px   = l & 15;      // fragment col; real pixel = px & 7
    const int quad = l >> 4;
    const int tile = blockIdx.x;
    const int b    = tile >> 7;               // 4 batches * 128 tiles
    const int hw0  = (tile & 127) << 3;       // 8 real px per tile

    // ---- one-time: H init (uniform h0) ----
    for (int k = t; k < 16 * COUT; k += NTHR) {
        const int p = k / COUT;
        const int j = k - p * COUT;
        const float v = h0[j];
        const unsigned short hi = bf_hi(v);
        Hb_hi[p][j] = hi;
        Hb_lo[p][j] = bf_rn(v - bf_f(hi));
    }

    // ---- one-time: S1 A-frags from global: W[i=wid*16+px][j=ks*32+quad*8+e] ----
    bf16x8 a1h0, a1l0, a1h1, a1l1, a1h2, a1l2;
    if (wid < 4) {
        const float* wrow = &w[(wid * 16 + px) * COUT + quad * 8];
        float v[8];
        #pragma unroll
        for (int e = 0; e < 8; ++e) v[e] = wrow[e];
        split8(v, a1h0, a1l0);
        #pragma unroll
        for (int e = 0; e < 8; ++e) v[e] = wrow[32 + e];
        split8(v, a1h1, a1l1);
        #pragma unroll
        for (int e = 0; e < 8; ++e) v[e] = wrow[64 + e];
        split8(v, a1h2, a1l2);
    }
    // ---- one-time: S2 A-frags: W^T[j=wid*16+px][i=ks*32+quad*8+e] (strided) ----
    bf16x8 a2h0, a2l0, a2h1, a2l1;
    const int j0s2 = wid * 16 + quad * 4;      // S2 D rows (j)
    if (wid < 6) {
        const int jcol = wid * 16 + px;
        float v[8];
        #pragma unroll
        for (int e = 0; e < 8; ++e) v[e] = w[(quad * 8 + e) * COUT + jcol];
        split8(v, a2h0, a2l0);
        #pragma unroll
        for (int e = 0; e < 8; ++e) v[e] = w[(32 + quad * 8 + e) * COUT + jcol];
        split8(v, a2h1, a2l1);
    }

    // x at S1 D positions; real pixel = px&7 (cols 8-15 duplicate cols 0-7)
    float xq0 = 0.f, xq1 = 0.f, xq2 = 0.f, xq3 = 0.f;
    if (wid < 4) {
        const size_t base = ((size_t)b * CIN + wid * 16 + quad * 4) * HW_ + hw0 + (px & 7);
        xq0 = x[base]; xq1 = x[base + HW_]; xq2 = x[base + 2 * HW_]; xq3 = x[base + 3 * HW_];
    }
    // h fp32 in regs at S2 D positions (rows j = j0s2.., col px)
    float hr0 = 0.f, hr1 = 0.f, hr2 = 0.f, hr3 = 0.f;
    if (wid < 6) {
        hr0 = h0[j0s2]; hr1 = h0[j0s2 + 1]; hr2 = h0[j0s2 + 2]; hr3 = h0[j0s2 + 3];
    }
    __syncthreads();

    #pragma unroll 1
    for (int it = 0; it < NITER; ++it) {
        // ---- stage 1 (waves 0-3): denom = W·H (9 MFMA); t = x*rcp(denom+eps) ----
        if (wid < 4) {
            f32x4 acc = {0.f, 0.f, 0.f, 0.f};
            {
                const bf16x8 bh = *(const bf16x8*)&Hb_hi[px][quad * 8];
                const bf16x8 bl = *(const bf16x8*)&Hb_lo[px][quad * 8];
                acc = __builtin_amdgcn_mfma_f32_16x16x32_bf16(a1h0, bh, acc, 0, 0, 0);
                acc = __builtin_amdgcn_mfma_f32_16x16x32_bf16(a1l0, bh, acc, 0, 0, 0);
                acc = __builtin_amdgcn_mfma_f32_16x16x32_bf16(a1h0, bl, acc, 0, 0, 0);
            }
            {
                const bf16x8 bh = *(const bf16x8*)&Hb_hi[px][32 + quad * 8];
                const bf16x8 bl = *(const bf16x8*)&Hb_lo[px][32 + quad * 8];
                acc = __builtin_amdgcn_mfma_f32_16x16x32_bf16(a1h1, bh, acc, 0, 0, 0);
                acc = __builtin_amdgcn_mfma_f32_16x16x32_bf16(a1l1, bh, acc, 0, 0, 0);
                acc = __builtin_amdgcn_mfma_f32_16x16x32_bf16(a1h1, bl, acc, 0, 0, 0);
            }
            {
                const bf16x8 bh = *(const bf16x8*)&Hb_hi[px][64 + quad * 8];
                const bf16x8 bl = *(const bf16x8*)&Hb_lo[px][64 + quad * 8];
                acc = __builtin_amdgcn_mfma_f32_16x16x32_bf16(a1h2, bh, acc, 0, 0, 0);
                acc = __builtin_amdgcn_mfma_f32_16x16x32_bf16(a1l2, bh, acc, 0, 0, 0);
                acc = __builtin_amdgcn_mfma_f32_16x16x32_bf16(a1h2, bl, acc, 0, 0, 0);
            }
            const float t0 = xq0 * __builtin_amdgcn_rcpf(acc[0] + NMF_EPS);
            const float t1 = xq1 * __builtin_amdgcn_rcpf(acc[1] + NMF_EPS);
            const float t2 = xq2 * __builtin_amdgcn_rcpf(acc[2] + NMF_EPS);
            const float t3 = xq3 * __builtin_amdgcn_rcpf(acc[3] + NMF_EPS);
            const int i0 = wid * 16 + quad * 4;
            ushort4 th, tl;
            th.x = bf_hi(t0); tl.x = bf_rn(t0 - bf_f(th.x));
            th.y = bf_hi(t1); tl.y = bf_rn(t1 - bf_f(th.y));
            th.z = bf_hi(t2); tl.z = bf_rn(t2 - bf_f(th.z));
            th.w = bf_hi(t3); tl.w = bf_rn(t3 - bf_f(th.w));
            *(ushort4*)&Tb_hi[px][i0] = th;
            *(ushort4*)&Tb_lo[px][i0] = tl;
        }
        __syncthreads();   // Tb ready

        // ---- stage 2 (waves 0-5): u = W^T·T (6 MFMA); h' = h(1+u); row sums ----
        float hp0 = 0.f, hp1 = 0.f, hp2 = 0.f, hp3 = 0.f;
        if (wid < 6) {
            f32x4 acc = {0.f, 0.f, 0.f, 0.f};
            {
                const bf16x8 bh = *(const bf16x8*)&Tb_hi[px][quad * 8];
                const bf16x8 bl = *(const bf16x8*)&Tb_lo[px][quad * 8];
                acc = __builtin_amdgcn_mfma_f32_16x16x32_bf16(a2h0, bh, acc, 0, 0, 0);
                acc = __builtin_amdgcn_mfma_f32_16x16x32_bf16(a2l0, bh, acc, 0, 0, 0);
                acc = __builtin_amdgcn_mfma_f32_16x16x32_bf16(a2h0, bl, acc, 0, 0, 0);
            }
            {
                const bf16x8 bh = *(const bf16x8*)&Tb_hi[px][32 + quad * 8];
                const bf16x8 bl = *(const bf16x8*)&Tb_lo[px][32 + quad * 8];
                acc = __builtin_amdgcn_mfma_f32_16x16x32_bf16(a2h1, bh, acc, 0, 0, 0);
                acc = __builtin_amdgcn_mfma_f32_16x16x32_bf16(a2l1, bh, acc, 0, 0, 0);
                acc = __builtin_amdgcn_mfma_f32_16x16x32_bf16(a2h1, bl, acc, 0, 0, 0);
            }
            hp0 = hr0 * (1.f + acc[0]);
            hp1 = hr1 * (1.f + acc[1]);
            hp2 = hr2 * (1.f + acc[2]);
            hp3 = hr3 * (1.f + acc[3]);
            float s = (hp0 + hp1) + (hp2 + hp3);
            s += __shfl_xor(s, 16, 64);
            s += __shfl_xor(s, 32, 64);
            if (l < 16) Par[wid][l] = s;
        }
        __syncthreads();   // Par ready

        if (wid < 6) {
            const float tot = NMF_EPS +
                ((Par[0][px] + Par[1][px]) + (Par[2][px] + Par[3][px])) +
                (Par[4][px] + Par[5][px]);
            const float inv = __builtin_amdgcn_rcpf(tot);
            hr0 = hp0 * inv; hr1 = hp1 * inv; hr2 = hp2 * inv; hr3 = hp3 * inv;
            if (it < NITER - 1) {
                ushort4 hh, hl;
                hh.x = bf_hi(hr0); hl.x = bf_rn(hr0 - bf_f(hh.x));
                hh.y = bf_hi(hr1); hl.y = bf_rn(hr1 - bf_f(hh.y));
                hh.z = bf_hi(hr2); hl.z = bf_rn(hr2 - bf_f(hh.z));
                hh.w = bf_hi(hr3); hl.w = bf_rn(hr3 - bf_f(hh.w));
                *(ushort4*)&Hb_hi[px][j0s2] = hh;
                *(ushort4*)&Hb_lo[px][j0s2] = hl;
            }
        }
        __syncthreads();   // Hb ready
    }

    // ---- write h (fp32 regs) -> out; cols 8-15 are duplicates, skip ----
    if (wid < 6 && px < 8) {
        const size_t base = ((size_t)b * COUT + j0s2) * HW_ + hw0 + px;
        out[base]           = hr0;
        out[base + HW_]     = hr1;
        out[base + 2 * HW_] = hr2;
        out[base + 3 * HW_] = hr3;
    }
}

extern "C" void kernel_launch(void* const* d_in, const int* in_sizes, int n_in,
                              void* d_out, int out_size, void* d_ws, size_t ws_size,
                              hipStream_t stream) {
    const float* x  = (const float*)d_in[0];
    const float* w  = (const float*)d_in[1];
    const float* h0 = (const float*)d_in[2];
    float* out = (float*)d_out;
    nmf_kernel<<<512, NTHR, 0, stream>>>(x, w, h0, out);
}

// Round 25
// 11.651 us; speedup vs baseline: 1.2695x; 1.2695x over previous
//
#include <hip/hip_runtime.h>

#define CIN 64
#define COUT 96
#define HW_  1024
#define NTHR 512
#define NITER 5
#define NMF_EPS 1e-20f

// Round-23: R21 (12.38us) + deferred normalization. h = g/S tracked
// algebraically: t = x*S*rcp(W.g+eps) equals reference t exactly, so the
// normalize phase (Par read + scale + Hb write) merges into phases A/B ->
// 2 barriers/iter (was 3). MFMA chains split into independent accumulators
// (9->3x3, 6->2x3) to cut dependency latency. Grid 256 (R22's 2-block split
// regressed: prologue doubling > barrier overlap).
typedef short bf16x8 __attribute__((ext_vector_type(8)));
typedef float f32x4  __attribute__((ext_vector_type(4)));

__device__ __forceinline__ unsigned short bf_hi(float x) {
    return (unsigned short)(__float_as_uint(x) >> 16);
}
__device__ __forceinline__ float bf_f(unsigned short u) {
    return __uint_as_float(((unsigned int)u) << 16);
}
__device__ __forceinline__ unsigned short bf_rn(float x) {
    unsigned int b = __float_as_uint(x);
    b += 0x7FFF + ((b >> 16) & 1);
    return (unsigned short)(b >> 16);
}
__device__ __forceinline__ void split8(const float* v, bf16x8& hi, bf16x8& lo) {
    #pragma unroll
    for (int e = 0; e < 8; ++e) {
        const unsigned short h = bf_hi(v[e]);
        hi[e] = (short)h;
        lo[e] = (short)bf_rn(v[e] - bf_f(h));
    }
}

__global__ __launch_bounds__(NTHR) void nmf_kernel(
    const float* __restrict__ x,
    const float* __restrict__ w,
    const float* __restrict__ h0,
    float* __restrict__ out)
{
    __shared__ unsigned short Hb_hi[16][104], Hb_lo[16][104];  // g as [px][j]
    __shared__ unsigned short Tb_hi[16][72],  Tb_lo[16][72];   // T as [px][i]
    __shared__ float Par[6][16];                               // per-wave g-partials

    const int t    = threadIdx.x;
    const int wid  = t >> 6;
    const int l    = t & 63;
    const int px   = l & 15;
    const int quad = l >> 4;
    const int tile = blockIdx.x;
    const int b    = tile >> 6;
    const int hw0  = (tile & 63) << 4;

    // ---- one-time: g0 = h0 into Hb ----
    for (int k = t; k < 16 * COUT; k += NTHR) {
        const int p = k / COUT;
        const int j = k - p * COUT;
        const float v = h0[j];
        const unsigned short hi = bf_hi(v);
        Hb_hi[p][j] = hi;
        Hb_lo[p][j] = bf_rn(v - bf_f(hi));
    }

    // ---- one-time: S1 A-frags: W[i=wid*16+px][j=ks*32+quad*8+e] ----
    bf16x8 a1h0, a1l0, a1h1, a1l1, a1h2, a1l2;
    if (wid < 4) {
        const float* wrow = &w[(wid * 16 + px) * COUT + quad * 8];
        float v[8];
        #pragma unroll
        for (int e = 0; e < 8; ++e) v[e] = wrow[e];
        split8(v, a1h0, a1l0);
        #pragma unroll
        for (int e = 0; e < 8; ++e) v[e] = wrow[32 + e];
        split8(v, a1h1, a1l1);
        #pragma unroll
        for (int e = 0; e < 8; ++e) v[e] = wrow[64 + e];
        split8(v, a1h2, a1l2);
    }
    // ---- one-time: S2 A-frags: W^T[j=wid*16+px][i=ks*32+quad*8+e] ----
    bf16x8 a2h0, a2l0, a2h1, a2l1;
    const int j0s2 = wid * 16 + quad * 4;
    if (wid < 6) {
        const int jcol = wid * 16 + px;
        float v[8];
        #pragma unroll
        for (int e = 0; e < 8; ++e) v[e] = w[(quad * 8 + e) * COUT + jcol];
        split8(v, a2h0, a2l0);
        #pragma unroll
        for (int e = 0; e < 8; ++e) v[e] = w[(32 + quad * 8 + e) * COUT + jcol];
        split8(v, a2h1, a2l1);
    }

    // x at S1 D positions
    float xq0 = 0.f, xq1 = 0.f, xq2 = 0.f, xq3 = 0.f;
    if (wid < 4) {
        const size_t base = ((size_t)b * CIN + wid * 16 + quad * 4) * HW_ + hw0 + px;
        xq0 = x[base]; xq1 = x[base + HW_]; xq2 = x[base + 2 * HW_]; xq3 = x[base + 3 * HW_];
    }
    // g fp32 in regs at S2 D positions; initial Par partials (S0 = 1)
    float gr0 = 0.f, gr1 = 0.f, gr2 = 0.f, gr3 = 0.f;
    if (wid < 6) {
        gr0 = h0[j0s2]; gr1 = h0[j0s2 + 1]; gr2 = h0[j0s2 + 2]; gr3 = h0[j0s2 + 3];
        float s = (gr0 + gr1) + (gr2 + gr3);
        s += __shfl_xor(s, 16, 64);
        s += __shfl_xor(s, 32, 64);
        if (l < 16) Par[wid][l] = s;
    }
    __syncthreads();

    #pragma unroll 1
    for (int it = 0; it < NITER; ++it) {
        // ---- phase A (waves 0-3): S from Par; denom_g = W·g; t = x·S·rcp ----
        if (wid < 4) {
            const float S = ((Par[0][px] + Par[1][px]) + (Par[2][px] + Par[3][px]))
                          + (Par[4][px] + Par[5][px]);
            f32x4 acc0 = {0.f, 0.f, 0.f, 0.f}, acc1 = acc0, acc2 = acc0;
            {
                const bf16x8 bh = *(const bf16x8*)&Hb_hi[px][quad * 8];
                const bf16x8 bl = *(const bf16x8*)&Hb_lo[px][quad * 8];
                acc0 = __builtin_amdgcn_mfma_f32_16x16x32_bf16(a1h0, bh, acc0, 0, 0, 0);
                acc1 = __builtin_amdgcn_mfma_f32_16x16x32_bf16(a1l0, bh, acc1, 0, 0, 0);
                acc2 = __builtin_amdgcn_mfma_f32_16x16x32_bf16(a1h0, bl, acc2, 0, 0, 0);
            }
            {
                const bf16x8 bh = *(const bf16x8*)&Hb_hi[px][32 + quad * 8];
                const bf16x8 bl = *(const bf16x8*)&Hb_lo[px][32 + quad * 8];
                acc0 = __builtin_amdgcn_mfma_f32_16x16x32_bf16(a1h1, bh, acc0, 0, 0, 0);
                acc1 = __builtin_amdgcn_mfma_f32_16x16x32_bf16(a1l1, bh, acc1, 0, 0, 0);
                acc2 = __builtin_amdgcn_mfma_f32_16x16x32_bf16(a1h1, bl, acc2, 0, 0, 0);
            }
            {
                const bf16x8 bh = *(const bf16x8*)&Hb_hi[px][64 + quad * 8];
                const bf16x8 bl = *(const bf16x8*)&Hb_lo[px][64 + quad * 8];
                acc0 = __builtin_amdgcn_mfma_f32_16x16x32_bf16(a1h2, bh, acc0, 0, 0, 0);
                acc1 = __builtin_amdgcn_mfma_f32_16x16x32_bf16(a1l2, bh, acc1, 0, 0, 0);
                acc2 = __builtin_amdgcn_mfma_f32_16x16x32_bf16(a1h2, bl, acc2, 0, 0, 0);
            }
            const float d0 = (acc0[0] + acc1[0]) + acc2[0];
            const float d1 = (acc0[1] + acc1[1]) + acc2[1];
            const float d2 = (acc0[2] + acc1[2]) + acc2[2];
            const float d3 = (acc0[3] + acc1[3]) + acc2[3];
            const float t0 = (xq0 * S) * __builtin_amdgcn_rcpf(d0 + NMF_EPS);
            const float t1 = (xq1 * S) * __builtin_amdgcn_rcpf(d1 + NMF_EPS);
            const float t2 = (xq2 * S) * __builtin_amdgcn_rcpf(d2 + NMF_EPS);
            const float t3 = (xq3 * S) * __builtin_amdgcn_rcpf(d3 + NMF_EPS);
            const int i0 = wid * 16 + quad * 4;
            ushort4 th, tl;
            th.x = bf_hi(t0); tl.x = bf_rn(t0 - bf_f(th.x));
            th.y = bf_hi(t1); tl.y = bf_rn(t1 - bf_f(th.y));
            th.z = bf_hi(t2); tl.z = bf_rn(t2 - bf_f(th.z));
            th.w = bf_hi(t3); tl.w = bf_rn(t3 - bf_f(th.w));
            *(ushort4*)&Tb_hi[px][i0] = th;
            *(ushort4*)&Tb_lo[px][i0] = tl;
        }
        __syncthreads();   // Tb ready

        // ---- phase B (waves 0-5): u = W^T·T; g' = g(1+u); Par partials ----
        if (wid < 6) {
            f32x4 acc0 = {0.f, 0.f, 0.f, 0.f}, acc1 = acc0;
            {
                const bf16x8 bh = *(const bf16x8*)&Tb_hi[px][quad * 8];
                const bf16x8 bl = *(const bf16x8*)&Tb_lo[px][quad * 8];
                acc0 = __builtin_amdgcn_mfma_f32_16x16x32_bf16(a2h0, bh, acc0, 0, 0, 0);
                acc1 = __builtin_amdgcn_mfma_f32_16x16x32_bf16(a2l0, bh, acc1, 0, 0, 0);
                acc0 = __builtin_amdgcn_mfma_f32_16x16x32_bf16(a2h0, bl, acc0, 0, 0, 0);
            }
            {
                const bf16x8 bh = *(const bf16x8*)&Tb_hi[px][32 + quad * 8];
                const bf16x8 bl = *(const bf16x8*)&Tb_lo[px][32 + quad * 8];
                acc0 = __builtin_amdgcn_mfma_f32_16x16x32_bf16(a2h1, bh, acc0, 0, 0, 0);
                acc1 = __builtin_amdgcn_mfma_f32_16x16x32_bf16(a2l1, bh, acc1, 0, 0, 0);
                acc0 = __builtin_amdgcn_mfma_f32_16x16x32_bf16(a2h1, bl, acc0, 0, 0, 0);
            }
            gr0 = gr0 * (1.f + (acc0[0] + acc1[0]));
            gr1 = gr1 * (1.f + (acc0[1] + acc1[1]));
            gr2 = gr2 * (1.f + (acc0[2] + acc1[2]));
            gr3 = gr3 * (1.f + (acc0[3] + acc1[3]));
            float s = (gr0 + gr1) + (gr2 + gr3);
            s += __shfl_xor(s, 16, 64);
            s += __shfl_xor(s, 32, 64);
            if (l < 16) Par[wid][l] = s;
            if (it < NITER - 1) {
                ushort4 hh, hl;
                hh.x = bf_hi(gr0); hl.x = bf_rn(gr0 - bf_f(hh.x));
                hh.y = bf_hi(gr1); hl.y = bf_rn(gr1 - bf_f(hh.y));
                hh.z = bf_hi(gr2); hl.z = bf_rn(gr2 - bf_f(hh.z));
                hh.w = bf_hi(gr3); hl.w = bf_rn(gr3 - bf_f(hh.w));
                *(ushort4*)&Hb_hi[px][j0s2] = hh;
                *(ushort4*)&Hb_lo[px][j0s2] = hl;
            }
        }
        __syncthreads();   // Par (+Hb) ready
    }

    // ---- epilogue: h = g * rcp(S_final); write out ----
    if (wid < 6) {
        const float Sf = ((Par[0][px] + Par[1][px]) + (Par[2][px] + Par[3][px]))
                       + (Par[4][px] + Par[5][px]) + NMF_EPS;
        const float inv = __builtin_amdgcn_rcpf(Sf);
        const size_t base = ((size_t)b * COUT + j0s2) * HW_ + hw0 + px;
        out[base]           = gr0 * inv;
        out[base + HW_]     = gr1 * inv;
        out[base + 2 * HW_] = gr2 * inv;
        out[base + 3 * HW_] = gr3 * inv;
    }
}

extern "C" void kernel_launch(void* const* d_in, const int* in_sizes, int n_in,
                              void* d_out, int out_size, void* d_ws, size_t ws_size,
                              hipStream_t stream) {
    const float* x  = (const float*)d_in[0];
    const float* w  = (const float*)d_in[1];
    const float* h0 = (const float*)d_in[2];
    float* out = (float*)d_out;
    nmf_kernel<<<256, NTHR, 0, stream>>>(x, w, h0, out);
}